// Round 7
// baseline (167.013 us; speedup 1.0000x reference)
//
#include <hip/hip_runtime.h>
#include <math.h>

// Problem constants (from reference): B=8, N=4096, K=26, D=64, all float32.
#define BB 8
#define NN 4096
#define KK 26
#define DD 64
#define CH 128           // N-chunks per batch -> grid = BB*CH = 1024 blocks
#define NPB (NN / CH)    // 32 n-rows per block
#define KD (KK * DD)     // 1664
#define KD4 (KD / 4)     // 416 = 13 * 32
#define NSLICE 13        // output slices per batch (13 * 32 float4 = KD4)

// ws layout: [0, BB*CH*KD) float partials, then BB int counters.
#define WS_PART_FLOATS (BB * CH * KD)
#define WS_CNT_OFF     ((size_t)WS_PART_FLOATS * 4)
#define WS_BYTES       (WS_CNT_OFF + BB * 4)

// out[b,k,d] = sigmoid( sum_n (t[b,n,d]*kn[d]+bn[d]) * (nb[b,n,k,d]*kt[d]+bt[d]) * a[b,n,k] )
//
// Lane mapping (main, k=0..23):  k = kk*4 + (lane>>4), d = (lane&15)*4 .. +3  (float4)
//   -> neighbor float4 index = kk*64 + lane  (contiguous 1KiB per wave instr)
// Lane mapping (tail, k=24,25):  k = 24 + (lane>>5), d = (lane&31)*2 .. +1    (float2)
//   -> neighbor float2 index = 768 + lane    (contiguous 512B)
//
// Fused: R3's stage-1 body, then the last 13 arriving blocks per batch each
// reduce one 32-float4 output slice (spin on the batch counter; all 1024
// blocks are co-resident: LDS 27KB -> 6 blocks/CU * 256 CU = 1536 slots).
__global__ __launch_bounds__(256) void gat_fused2(
    const float* __restrict__ targets,    // (B,N,D)
    const float* __restrict__ neighbors,  // (B,N,K,D)
    const float* __restrict__ a,          // (B,N,K)
    const float* __restrict__ kt, const float* __restrict__ bt,
    const float* __restrict__ kn, const float* __restrict__ bn,
    float* __restrict__ ws,               // (B,CH,KD) partials
    int*   __restrict__ cnt,              // (B) zeroed counters
    float* __restrict__ out)              // (B,KD)
{
    const int b     = blockIdx.x / CH;
    const int chunk = blockIdx.x % CH;
    const int tid   = threadIdx.x;
    const int wave  = tid >> 6;
    const int lane  = tid & 63;

    const int g16 = lane >> 4, r16 = lane & 15;
    const int g32 = lane >> 5, r32 = lane & 31;

    const float4 kt4 = ((const float4*)kt)[r16];
    const float4 bt4 = ((const float4*)bt)[r16];
    const float4 kn4 = ((const float4*)kn)[r16];
    const float4 bn4 = ((const float4*)bn)[r16];
    const float2 kt2 = ((const float2*)kt)[r32];
    const float2 bt2 = ((const float2*)bt)[r32];
    const float2 kn2 = ((const float2*)kn)[r32];
    const float2 bn2 = ((const float2*)bn)[r32];

    float4 acc4[6];
#pragma unroll
    for (int kk = 0; kk < 6; ++kk) acc4[kk] = make_float4(0.f, 0.f, 0.f, 0.f);
    float2 accT = make_float2(0.f, 0.f);

    const int n0 = chunk * NPB;
    for (int n = n0 + wave; n < n0 + NPB; n += 4) {
        const size_t row = (size_t)(b * NN + n);
        const float4 t4 = ((const float4*)(targets + row * DD))[r16];
        const float2 t2 = ((const float2*)(targets + row * DD))[r32];
        float4 tt4;
        tt4.x = fmaf(t4.x, kn4.x, bn4.x);
        tt4.y = fmaf(t4.y, kn4.y, bn4.y);
        tt4.z = fmaf(t4.z, kn4.z, bn4.z);
        tt4.w = fmaf(t4.w, kn4.w, bn4.w);
        float2 tt2;
        tt2.x = fmaf(t2.x, kn2.x, bn2.x);
        tt2.y = fmaf(t2.y, kn2.y, bn2.y);

        const float4* __restrict__ nbrow4 = (const float4*)(neighbors + row * (size_t)KD);
        const float*  __restrict__ arow   = a + row * KK;
#pragma unroll
        for (int kk = 0; kk < 6; ++kk) {
            const float  av = arow[kk * 4 + g16];
            const float4 v  = nbrow4[kk * 64 + lane];
            acc4[kk].x = fmaf(tt4.x * av, fmaf(v.x, kt4.x, bt4.x), acc4[kk].x);
            acc4[kk].y = fmaf(tt4.y * av, fmaf(v.y, kt4.y, bt4.y), acc4[kk].y);
            acc4[kk].z = fmaf(tt4.z * av, fmaf(v.z, kt4.z, bt4.z), acc4[kk].z);
            acc4[kk].w = fmaf(tt4.w * av, fmaf(v.w, kt4.w, bt4.w), acc4[kk].w);
        }
        {
            const float  av = arow[24 + g32];
            const float2 v  = ((const float2*)nbrow4)[768 + lane];
            accT.x = fmaf(tt2.x * av, fmaf(v.x, kt2.x, bt2.x), accT.x);
            accT.y = fmaf(tt2.y * av, fmaf(v.y, kt2.y, bt2.y), accT.y);
        }
    }

    // Cross-wave reduction in LDS, block partial -> ws (plain float4 stores).
    __shared__ float lds[4][KD];
#pragma unroll
    for (int kk = 0; kk < 6; ++kk)
        ((float4*)lds[wave])[kk * 64 + lane] = acc4[kk];
    ((float2*)lds[wave])[768 + lane] = accT;
    __syncthreads();

    float4* __restrict__ wrow4 = (float4*)(ws + ((size_t)b * CH + chunk) * KD);
    for (int i4 = tid; i4 < KD4; i4 += 256) {
        const float4 v0 = ((const float4*)lds[0])[i4];
        const float4 v1 = ((const float4*)lds[1])[i4];
        const float4 v2 = ((const float4*)lds[2])[i4];
        const float4 v3 = ((const float4*)lds[3])[i4];
        float4 s;
        s.x = (v0.x + v1.x) + (v2.x + v3.x);
        s.y = (v0.y + v1.y) + (v2.y + v3.y);
        s.z = (v0.z + v1.z) + (v2.z + v3.z);
        s.w = (v0.w + v1.w) + (v2.w + v3.w);
        wrow4[i4] = s;
    }

    // Release our partial, claim an arrival ticket.
    __threadfence();
    __shared__ int sh_ret;
    if (tid == 0) sh_ret = atomicAdd(&cnt[b], 1);
    __syncthreads();
    const int ret = sh_ret;
    if (ret < CH - NSLICE) return;

    // We are one of the last NSLICE arrivals: own slice = ret - (CH-NSLICE).
    const int slice = ret - (CH - NSLICE);
    if (tid == 0) {
        while (__hip_atomic_load(&cnt[b], __ATOMIC_RELAXED, __HIP_MEMORY_SCOPE_AGENT) < CH)
            __builtin_amdgcn_s_sleep(8);
    }
    __syncthreads();
    __threadfence();   // acquire: invalidate caches before reading other blocks' partials

    const int o = tid & 31;
    const int g = tid >> 5;               // 0..7
    const float4* __restrict__ ws4 = (const float4*)ws;
    const size_t base = (size_t)b * CH * KD4 + (size_t)slice * 32 + o;

    float4 s = make_float4(0.f, 0.f, 0.f, 0.f);
#pragma unroll
    for (int i = 0; i < CH / 8; ++i) {    // 16 chunks per thread
        const int c = g + i * 8;
        const float4 v = ws4[base + (size_t)c * KD4];
        s.x += v.x; s.y += v.y; s.z += v.z; s.w += v.w;
    }

    float4* lds4 = (float4*)lds[0];       // reuse stage-1 LDS (done with it)
    __syncthreads();
    lds4[g * 32 + o] = s;
    __syncthreads();

    if (tid < 32) {
        float4 t = lds4[o];
#pragma unroll
        for (int gg = 1; gg < 8; ++gg) {
            const float4 v = lds4[gg * 32 + o];
            t.x += v.x; t.y += v.y; t.z += v.z; t.w += v.w;
        }
        float4 oo;
        oo.x = 1.f / (1.f + expf(-t.x));
        oo.y = 1.f / (1.f + expf(-t.y));
        oo.z = 1.f / (1.f + expf(-t.z));
        oo.w = 1.f / (1.f + expf(-t.w));
        ((float4*)out)[(size_t)b * KD4 + (size_t)slice * 32 + o] = oo;
    }
}

// ---------------- proven R3 fallback (two kernels), if ws too small ----------------
__global__ __launch_bounds__(256) void gat_partial_ws(
    const float* __restrict__ targets, const float* __restrict__ neighbors,
    const float* __restrict__ a,
    const float* __restrict__ kt, const float* __restrict__ bt,
    const float* __restrict__ kn, const float* __restrict__ bn,
    float* __restrict__ ws)
{
    const int b     = blockIdx.x / CH;
    const int chunk = blockIdx.x % CH;
    const int tid   = threadIdx.x;
    const int wave  = tid >> 6;
    const int lane  = tid & 63;
    const int g16 = lane >> 4, r16 = lane & 15;
    const int g32 = lane >> 5, r32 = lane & 31;

    const float4 kt4 = ((const float4*)kt)[r16];
    const float4 bt4 = ((const float4*)bt)[r16];
    const float4 kn4 = ((const float4*)kn)[r16];
    const float4 bn4 = ((const float4*)bn)[r16];
    const float2 kt2 = ((const float2*)kt)[r32];
    const float2 bt2 = ((const float2*)bt)[r32];
    const float2 kn2 = ((const float2*)kn)[r32];
    const float2 bn2 = ((const float2*)bn)[r32];

    float4 acc4[6];
#pragma unroll
    for (int kk = 0; kk < 6; ++kk) acc4[kk] = make_float4(0.f, 0.f, 0.f, 0.f);
    float2 accT = make_float2(0.f, 0.f);

    const int n0 = chunk * NPB;
    for (int n = n0 + wave; n < n0 + NPB; n += 4) {
        const size_t row = (size_t)(b * NN + n);
        const float4 t4 = ((const float4*)(targets + row * DD))[r16];
        const float2 t2 = ((const float2*)(targets + row * DD))[r32];
        float4 tt4;
        tt4.x = fmaf(t4.x, kn4.x, bn4.x);
        tt4.y = fmaf(t4.y, kn4.y, bn4.y);
        tt4.z = fmaf(t4.z, kn4.z, bn4.z);
        tt4.w = fmaf(t4.w, kn4.w, bn4.w);
        float2 tt2;
        tt2.x = fmaf(t2.x, kn2.x, bn2.x);
        tt2.y = fmaf(t2.y, kn2.y, bn2.y);

        const float4* __restrict__ nbrow4 = (const float4*)(neighbors + row * (size_t)KD);
        const float*  __restrict__ arow   = a + row * KK;
#pragma unroll
        for (int kk = 0; kk < 6; ++kk) {
            const float  av = arow[kk * 4 + g16];
            const float4 v  = nbrow4[kk * 64 + lane];
            acc4[kk].x = fmaf(tt4.x * av, fmaf(v.x, kt4.x, bt4.x), acc4[kk].x);
            acc4[kk].y = fmaf(tt4.y * av, fmaf(v.y, kt4.y, bt4.y), acc4[kk].y);
            acc4[kk].z = fmaf(tt4.z * av, fmaf(v.z, kt4.z, bt4.z), acc4[kk].z);
            acc4[kk].w = fmaf(tt4.w * av, fmaf(v.w, kt4.w, bt4.w), acc4[kk].w);
        }
        {
            const float  av = arow[24 + g32];
            const float2 v  = ((const float2*)nbrow4)[768 + lane];
            accT.x = fmaf(tt2.x * av, fmaf(v.x, kt2.x, bt2.x), accT.x);
            accT.y = fmaf(tt2.y * av, fmaf(v.y, kt2.y, bt2.y), accT.y);
        }
    }

    __shared__ float lds[4][KD];
#pragma unroll
    for (int kk = 0; kk < 6; ++kk)
        ((float4*)lds[wave])[kk * 64 + lane] = acc4[kk];
    ((float2*)lds[wave])[768 + lane] = accT;
    __syncthreads();

    float4* __restrict__ wrow4 = (float4*)(ws + ((size_t)b * CH + chunk) * KD);
    for (int i4 = tid; i4 < KD4; i4 += 256) {
        const float4 v0 = ((const float4*)lds[0])[i4];
        const float4 v1 = ((const float4*)lds[1])[i4];
        const float4 v2 = ((const float4*)lds[2])[i4];
        const float4 v3 = ((const float4*)lds[3])[i4];
        float4 s;
        s.x = (v0.x + v1.x) + (v2.x + v3.x);
        s.y = (v0.y + v1.y) + (v2.y + v3.y);
        s.z = (v0.z + v1.z) + (v2.z + v3.z);
        s.w = (v0.w + v1.w) + (v2.w + v3.w);
        wrow4[i4] = s;
    }
}

__global__ __launch_bounds__(256) void gat_reduce_sigmoid(
    const float* __restrict__ ws, float* __restrict__ out)
{
    const int b    = blockIdx.x / 13;
    const int jblk = blockIdx.x % 13;
    const int tid  = threadIdx.x;
    const int o    = tid & 31;
    const int g    = tid >> 5;

    const float4* __restrict__ ws4 = (const float4*)ws;
    const size_t base = (size_t)b * CH * KD4 + (size_t)jblk * 32 + o;

    float4 s = make_float4(0.f, 0.f, 0.f, 0.f);
#pragma unroll
    for (int i = 0; i < CH / 8; ++i) {
        const int c = g + i * 8;
        const float4 v = ws4[base + (size_t)c * KD4];
        s.x += v.x; s.y += v.y; s.z += v.z; s.w += v.w;
    }

    __shared__ float4 lds4[8][32];
    lds4[g][o] = s;
    __syncthreads();

    if (tid < 32) {
        float4 t = lds4[0][o];
#pragma unroll
        for (int gg = 1; gg < 8; ++gg) {
            const float4 v = lds4[gg][o];
            t.x += v.x; t.y += v.y; t.z += v.z; t.w += v.w;
        }
        float4 oo;
        oo.x = 1.f / (1.f + expf(-t.x));
        oo.y = 1.f / (1.f + expf(-t.y));
        oo.z = 1.f / (1.f + expf(-t.z));
        oo.w = 1.f / (1.f + expf(-t.w));
        ((float4*)out)[(size_t)b * KD4 + (size_t)jblk * 32 + o] = oo;
    }
}

extern "C" void kernel_launch(void* const* d_in, const int* in_sizes, int n_in,
                              void* d_out, int out_size, void* d_ws, size_t ws_size,
                              hipStream_t stream) {
    const float* targets   = (const float*)d_in[0];
    const float* neighbors = (const float*)d_in[1];
    const float* a         = (const float*)d_in[2];
    const float* kt        = (const float*)d_in[3];
    const float* bt        = (const float*)d_in[4];
    const float* kn        = (const float*)d_in[5];
    const float* bn        = (const float*)d_in[6];
    float* out = (float*)d_out;

    if (ws_size >= WS_BYTES) {
        float* ws  = (float*)d_ws;
        int*   cnt = (int*)((char*)d_ws + WS_CNT_OFF);
        hipMemsetAsync(cnt, 0, BB * sizeof(int), stream);   // 32 B
        gat_fused2<<<BB * CH, 256, 0, stream>>>(targets, neighbors, a, kt, bt, kn, bn,
                                                ws, cnt, out);
    } else {
        float* ws = (float*)d_ws;
        gat_partial_ws<<<BB * CH, 256, 0, stream>>>(targets, neighbors, a, kt, bt, kn, bn, ws);
        gat_reduce_sigmoid<<<BB * 13, 256, 0, stream>>>(ws, out);
    }
}

// Round 8
// 41.906 us; speedup vs baseline: 3.9854x; 3.9854x over previous
//
#include <hip/hip_runtime.h>
#include <math.h>

// Problem constants (from reference): B=8, N=4096, K=26, D=64, all float32.
#define BB 8
#define NN 4096
#define KK 26
#define DD 64
#define CH 128           // N-chunks per batch -> grid = BB*CH = 1024 blocks
#define NPB (NN / CH)    // 32 n-rows per block
#define KD (KK * DD)     // 1664
#define KD4 (KD / 4)     // 416 = 13 * 32

// out[b,k,d] = sigmoid( sum_n (t[b,n,d]*kn[d]+bn[d]) * (nb[b,n,k,d]*kt[d]+bt[d]) * a[b,n,k] )
//
// Structure (measured best, R3 = 42.2 us):
//   stage-1: 1024 blocks x 256 thr (16 waves/CU), vectorized float4/float2
//            lane mapping, per-block partials -> ws (6.8 MB).
//   stage-2: 104 blocks reduce ws + sigmoid -> out.
// Measured on MI355X: stage-1 streams 237.5 MB at ~6.25 TB/s = ~99% of the
// m13 read ceiling (6.29 TB/s). Single-kernel fusions via device-scope
// atomics (R4) or fence handshakes (R7) regress 3-6x: per-block
// __threadfence() = L2 writeback/invalidate on non-coherent XCD L2s.
//
// Lane mapping (main, k=0..23):  k = kk*4 + (lane>>4), d = (lane&15)*4 .. +3  (float4)
//   -> neighbor float4 index = kk*64 + lane  (contiguous 1KiB per wave instr)
// Lane mapping (tail, k=24,25):  k = 24 + (lane>>5), d = (lane&31)*2 .. +1    (float2)
//   -> neighbor float2 index = 768 + lane    (contiguous 512B)
__global__ __launch_bounds__(256) void gat_partial_ws(
    const float* __restrict__ targets,    // (B,N,D)
    const float* __restrict__ neighbors,  // (B,N,K,D)
    const float* __restrict__ a,          // (B,N,K)
    const float* __restrict__ kt, const float* __restrict__ bt,
    const float* __restrict__ kn, const float* __restrict__ bn,
    float* __restrict__ ws)               // (B, CH, KD) partials
{
    const int b     = blockIdx.x / CH;
    const int chunk = blockIdx.x % CH;
    const int tid   = threadIdx.x;
    const int wave  = tid >> 6;
    const int lane  = tid & 63;

    const int g16 = lane >> 4, r16 = lane & 15;
    const int g32 = lane >> 5, r32 = lane & 31;

    const float4 kt4 = ((const float4*)kt)[r16];
    const float4 bt4 = ((const float4*)bt)[r16];
    const float4 kn4 = ((const float4*)kn)[r16];
    const float4 bn4 = ((const float4*)bn)[r16];
    const float2 kt2 = ((const float2*)kt)[r32];
    const float2 bt2 = ((const float2*)bt)[r32];
    const float2 kn2 = ((const float2*)kn)[r32];
    const float2 bn2 = ((const float2*)bn)[r32];

    float4 acc4[6];
#pragma unroll
    for (int kk = 0; kk < 6; ++kk) acc4[kk] = make_float4(0.f, 0.f, 0.f, 0.f);
    float2 accT = make_float2(0.f, 0.f);

    const int n0 = chunk * NPB;
    for (int n = n0 + wave; n < n0 + NPB; n += 4) {
        const size_t row = (size_t)(b * NN + n);
        const float4 t4 = ((const float4*)(targets + row * DD))[r16];
        const float2 t2 = ((const float2*)(targets + row * DD))[r32];
        float4 tt4;
        tt4.x = fmaf(t4.x, kn4.x, bn4.x);
        tt4.y = fmaf(t4.y, kn4.y, bn4.y);
        tt4.z = fmaf(t4.z, kn4.z, bn4.z);
        tt4.w = fmaf(t4.w, kn4.w, bn4.w);
        float2 tt2;
        tt2.x = fmaf(t2.x, kn2.x, bn2.x);
        tt2.y = fmaf(t2.y, kn2.y, bn2.y);

        const float4* __restrict__ nbrow4 = (const float4*)(neighbors + row * (size_t)KD);
        const float*  __restrict__ arow   = a + row * KK;
#pragma unroll
        for (int kk = 0; kk < 6; ++kk) {
            const float  av = arow[kk * 4 + g16];
            const float4 v  = nbrow4[kk * 64 + lane];
            acc4[kk].x = fmaf(tt4.x * av, fmaf(v.x, kt4.x, bt4.x), acc4[kk].x);
            acc4[kk].y = fmaf(tt4.y * av, fmaf(v.y, kt4.y, bt4.y), acc4[kk].y);
            acc4[kk].z = fmaf(tt4.z * av, fmaf(v.z, kt4.z, bt4.z), acc4[kk].z);
            acc4[kk].w = fmaf(tt4.w * av, fmaf(v.w, kt4.w, bt4.w), acc4[kk].w);
        }
        {
            const float  av = arow[24 + g32];
            const float2 v  = ((const float2*)nbrow4)[768 + lane];
            accT.x = fmaf(tt2.x * av, fmaf(v.x, kt2.x, bt2.x), accT.x);
            accT.y = fmaf(tt2.y * av, fmaf(v.y, kt2.y, bt2.y), accT.y);
        }
    }

    // Per-wave write to LDS at owned (k,d) slots, then cross-wave sum -> ws.
    __shared__ float lds[4][KD];
#pragma unroll
    for (int kk = 0; kk < 6; ++kk)
        ((float4*)lds[wave])[kk * 64 + lane] = acc4[kk];
    ((float2*)lds[wave])[768 + lane] = accT;
    __syncthreads();

    float4* __restrict__ wrow4 = (float4*)(ws + ((size_t)b * CH + chunk) * KD);
    for (int i4 = tid; i4 < KD4; i4 += 256) {
        const float4 v0 = ((const float4*)lds[0])[i4];
        const float4 v1 = ((const float4*)lds[1])[i4];
        const float4 v2 = ((const float4*)lds[2])[i4];
        const float4 v3 = ((const float4*)lds[3])[i4];
        float4 s;
        s.x = (v0.x + v1.x) + (v2.x + v3.x);
        s.y = (v0.y + v1.y) + (v2.y + v3.y);
        s.z = (v0.z + v1.z) + (v2.z + v3.z);
        s.w = (v0.w + v1.w) + (v2.w + v3.w);
        wrow4[i4] = s;
    }
}

// Parallel reduce + sigmoid: grid = BB*13 = 104 blocks, 256 threads.
// Block (b, jblk) owns 32 float4 outputs. tid = g*32 + o: thread sums 16
// chunks {g, g+8, ...}; lanes o=0..31 read 512B-contiguous segments.
__global__ __launch_bounds__(256) void gat_reduce_sigmoid(
    const float* __restrict__ ws, float* __restrict__ out)
{
    const int b    = blockIdx.x / 13;
    const int jblk = blockIdx.x % 13;
    const int tid  = threadIdx.x;
    const int o    = tid & 31;
    const int g    = tid >> 5;            // 0..7

    const float4* __restrict__ ws4 = (const float4*)ws;
    const size_t base = (size_t)b * CH * KD4 + (size_t)jblk * 32 + o;

    float4 s = make_float4(0.f, 0.f, 0.f, 0.f);
#pragma unroll
    for (int i = 0; i < CH / 8; ++i) {            // 16 chunks per thread
        const int c = g + i * 8;
        const float4 v = ws4[base + (size_t)c * KD4];
        s.x += v.x; s.y += v.y; s.z += v.z; s.w += v.w;
    }

    __shared__ float4 lds4[8][32];
    lds4[g][o] = s;
    __syncthreads();

    if (tid < 32) {
        float4 t = lds4[0][o];
#pragma unroll
        for (int gg = 1; gg < 8; ++gg) {
            const float4 v = lds4[gg][o];
            t.x += v.x; t.y += v.y; t.z += v.z; t.w += v.w;
        }
        float4 oo;
        oo.x = 1.f / (1.f + expf(-t.x));
        oo.y = 1.f / (1.f + expf(-t.y));
        oo.z = 1.f / (1.f + expf(-t.z));
        oo.w = 1.f / (1.f + expf(-t.w));
        ((float4*)out)[(size_t)b * KD4 + (size_t)jblk * 32 + o] = oo;
    }
}

// ---------------- fallback path (atomics), used only if ws too small ----------------
__global__ __launch_bounds__(256) void gat_partial_atomic(
    const float* __restrict__ targets, const float* __restrict__ neighbors,
    const float* __restrict__ a,
    const float* __restrict__ kt, const float* __restrict__ bt,
    const float* __restrict__ kn, const float* __restrict__ bn,
    float* __restrict__ out)
{
    const int b     = blockIdx.x / CH;
    const int chunk = blockIdx.x % CH;
    const int tid   = threadIdx.x;
    const int wave  = tid >> 6;
    const int lane  = tid & 63;
    const int d     = lane;
    const float kt_d = kt[d], bt_d = bt[d], kn_d = kn[d], bn_d = bn[d];
    float acc[KK];
#pragma unroll
    for (int k = 0; k < KK; ++k) acc[k] = 0.f;
    const int n0 = chunk * NPB;
    for (int n = n0 + wave; n < n0 + NPB; n += 4) {
        const size_t row = (size_t)(b * NN + n);
        const float tt = fmaf(targets[row * DD + d], kn_d, bn_d);
        const float* __restrict__ nbrow = neighbors + row * (size_t)KD;
        const float* __restrict__ arow  = a + row * KK;
#pragma unroll
        for (int k = 0; k < KK; ++k)
            acc[k] = fmaf(tt * arow[k], fmaf(nbrow[k * DD + d], kt_d, bt_d), acc[k]);
    }
    __shared__ float lds[4][KD];
#pragma unroll
    for (int k = 0; k < KK; ++k) lds[wave][k * DD + lane] = acc[k];
    __syncthreads();
    for (int idx = tid; idx < KD; idx += 256) {
        const float s = lds[0][idx] + lds[1][idx] + lds[2][idx] + lds[3][idx];
        atomicAdd(&out[b * KD + idx], s);
    }
}

__global__ __launch_bounds__(256) void gat_sigmoid(float* __restrict__ out, int nelem) {
    const int i = blockIdx.x * blockDim.x + threadIdx.x;
    if (i < nelem) out[i] = 1.f / (1.f + expf(-out[i]));
}

extern "C" void kernel_launch(void* const* d_in, const int* in_sizes, int n_in,
                              void* d_out, int out_size, void* d_ws, size_t ws_size,
                              hipStream_t stream) {
    const float* targets   = (const float*)d_in[0];
    const float* neighbors = (const float*)d_in[1];
    const float* a         = (const float*)d_in[2];
    const float* kt        = (const float*)d_in[3];
    const float* bt        = (const float*)d_in[4];
    const float* kn        = (const float*)d_in[5];
    const float* bn        = (const float*)d_in[6];
    float* out = (float*)d_out;

    const size_t ws_need = (size_t)BB * CH * KD * sizeof(float);  // 6.8 MB
    if (ws_size >= ws_need) {
        float* ws = (float*)d_ws;
        gat_partial_ws<<<BB * CH, 256, 0, stream>>>(targets, neighbors, a, kt, bt, kn, bn, ws);
        gat_reduce_sigmoid<<<BB * 13, 256, 0, stream>>>(ws, out);
    } else {
        hipMemsetAsync(d_out, 0, (size_t)out_size * sizeof(float), stream);
        gat_partial_atomic<<<BB * CH, 256, 0, stream>>>(targets, neighbors, a, kt, bt, kn, bn, out);
        gat_sigmoid<<<(out_size + 255) / 256, 256, 0, stream>>>(out, out_size);
    }
}